// Round 1
// baseline (1216.311 us; speedup 1.0000x reference)
//
#include <hip/hip_runtime.h>

#define BATCH   262144
#define NCODE   1024
#define DIM     64
#define BLOCK   256
#define NBLK    (BATCH / BLOCK)   // 1024 blocks for epilogue/loss
#define MARGIN  2e-4f

// ws layout (bytes):
// [0, 8192)            double partial[1024]
// [8192, 12288)        float  c2[1024]
// [12288, 274432)      uchar  flags[BATCH]
// [274432, 536576)     ushort pack[131072]  -- codebook bf16 hi/lo, fragment-major

typedef __attribute__((ext_vector_type(8))) short bf16x8;
typedef __attribute__((ext_vector_type(4))) float f32x4;

#define MFMA(a, b, c) __builtin_amdgcn_mfma_f32_16x16x32_bf16(a, b, c, 0, 0, 0)

// ---- exact c2 (numpy pairwise order, 8 accumulators) — unchanged, verified ----
__global__ void c2_kernel(const float* __restrict__ cb, float* __restrict__ c2) {
    int k = blockIdx.x * blockDim.x + threadIdx.x;
    if (k >= NCODE) return;
    const float* row = cb + (size_t)k * DIM;
    float r[8];
#pragma unroll
    for (int j = 0; j < 8; ++j) r[j] = __fmul_rn(row[j], row[j]);
#pragma unroll
    for (int i = 8; i < DIM; i += 8) {
#pragma unroll
        for (int j = 0; j < 8; ++j) r[j] = __fadd_rn(r[j], __fmul_rn(row[i + j], row[i + j]));
    }
    c2[k] = __fadd_rn(__fadd_rn(__fadd_rn(r[0], r[1]), __fadd_rn(r[2], r[3])),
                      __fadd_rn(__fadd_rn(r[4], r[5]), __fadd_rn(r[6], r[7])));
}

// fp32 -> bf16 hi (RNE) + bf16 lo (RNE of exact residual)
__device__ __forceinline__ void split1(float f, unsigned short& h, unsigned short& l) {
    unsigned u = __float_as_uint(f);
    unsigned r = (u + 0x7fffu + ((u >> 16) & 1u)) >> 16;
    h = (unsigned short)r;
    float hf = __uint_as_float(r << 16);
    float lo = f - hf;                      // exact (Sterbenz)
    unsigned u2 = __float_as_uint(lo);
    l = (unsigned short)((u2 + 0x7fffu + ((u2 >> 16) & 1u)) >> 16);
}

// ---- pack codebook into fragment-major bf16 hi/lo ----
// pack[((t*4 + q)*64 + lane)*8 + j], q = 2*s + p (s = k-step, p = 0:hi 1:lo)
// element j = part(cb[t*16 + (lane&15)][32*s + 8*(lane>>4) + j])
__global__ void pack_kernel(const float* __restrict__ cb, unsigned short* __restrict__ pack) {
    const int tid  = blockIdx.x * blockDim.x + threadIdx.x;   // 0..4095
    const int t    = tid >> 6, lane = tid & 63;
    const int c    = t * 16 + (lane & 15);
    const int g    = lane >> 4;
#pragma unroll
    for (int s = 0; s < 2; ++s) {
        const float* src = cb + (size_t)c * DIM + s * 32 + g * 8;
        bf16x8 hv, lv;
#pragma unroll
        for (int j = 0; j < 8; ++j) {
            unsigned short hh, ll; split1(src[j], hh, ll);
            hv[j] = (short)hh; lv[j] = (short)ll;
        }
        *(bf16x8*)(pack + ((size_t)(t * 4 + 2 * s + 0) * 64 + lane) * 8) = hv;
        *(bf16x8*)(pack + ((size_t)(t * 4 + 2 * s + 1) * 64 + lane) * 8) = lv;
    }
}

// ---- MFMA screening: per-row best/second-best of s(k) = c2[k] - 2*cross(k) ----
// wave = 32 rows (2 row-tiles of 16); block = 4 waves = 128 rows; grid = 2048
__global__ __launch_bounds__(256) void screen_kernel(
        const float* __restrict__ z, const unsigned short* __restrict__ pack,
        const float* __restrict__ c2, float* __restrict__ out_idx,
        unsigned char* __restrict__ flags)
{
    __shared__ unsigned short lds[16384];       // 32 KB = 8 tiles * 4 KB
    const int tid  = threadIdx.x;
    const int lane = tid & 63, wid = tid >> 6;
    const int col  = lane & 15, g = lane >> 4;
    const int rowbase = blockIdx.x * 128 + wid * 32;

    // A-frags: A[row = lane&15][k = 32*s + 8*g + j], held in VGPRs for whole kernel
    bf16x8 Ah[2][2], Al[2][2];
#pragma unroll
    for (int rt = 0; rt < 2; ++rt)
#pragma unroll
        for (int s = 0; s < 2; ++s) {
            const float* zp = z + (size_t)(rowbase + rt * 16 + col) * DIM + s * 32 + g * 8;
            float tmp[8];
            *(float4*)(tmp)     = ((const float4*)zp)[0];
            *(float4*)(tmp + 4) = ((const float4*)zp)[1];
            bf16x8 hv, lv;
#pragma unroll
            for (int j = 0; j < 8; ++j) {
                unsigned short hh, ll; split1(tmp[j], hh, ll);
                hv[j] = (short)hh; lv[j] = (short)ll;
            }
            Ah[rt][s] = hv; Al[rt][s] = lv;
        }

    float b1[8], b2[8], bk[8];
#pragma unroll
    for (int i = 0; i < 8; ++i) { b1[i] = __builtin_inff(); b2[i] = __builtin_inff(); bk[i] = 0.f; }
    float codef = (float)col;   // code = 16*t + col, tracked incrementally (exact in fp32)

#define UPD(i, sv) { const float s_ = (sv); const bool lt = s_ < b1[i]; \
                     b2[i] = fminf(b2[i], lt ? b1[i] : s_); \
                     bk[i] = lt ? codef : bk[i]; \
                     b1[i] = fminf(b1[i], s_); }

#pragma unroll 1
    for (int chunk = 0; chunk < 8; ++chunk) {
        if (chunk) __syncthreads();             // previous chunk fully consumed
        {   // stage 8 tiles (32 KB): each wave copies 8 x 1KB segments, fully coalesced
            const unsigned short* gs = pack + (size_t)chunk * 16384;
#pragma unroll
            for (int i = 0; i < 8; ++i) {
                const int seg = wid * 8 + i;
                bf16x8 v = *(const bf16x8*)(gs + seg * 512 + lane * 8);
                *(bf16x8*)(lds + seg * 512 + lane * 8) = v;
            }
        }
        __syncthreads();
#pragma unroll
        for (int tt = 0; tt < 8; ++tt) {
            const unsigned short* lb = lds + tt * 2048;
            bf16x8 Bh0 = *(const bf16x8*)(lb +    0 + lane * 8);
            bf16x8 Bl0 = *(const bf16x8*)(lb +  512 + lane * 8);
            bf16x8 Bh1 = *(const bf16x8*)(lb + 1024 + lane * 8);
            bf16x8 Bl1 = *(const bf16x8*)(lb + 1536 + lane * 8);
            const float c2v = c2[(chunk * 8 + tt) * 16 + col];
            f32x4 acc0 = {0.f, 0.f, 0.f, 0.f}, acc1 = {0.f, 0.f, 0.f, 0.f};
            // cross = zhi*chi + zhi*clo + zlo*chi  (lo*lo dropped, ~2^-18 rel)
            acc0 = MFMA(Ah[0][0], Bh0, acc0); acc0 = MFMA(Ah[0][1], Bh1, acc0);
            acc0 = MFMA(Ah[0][0], Bl0, acc0); acc0 = MFMA(Al[0][0], Bh0, acc0);
            acc0 = MFMA(Ah[0][1], Bl1, acc0); acc0 = MFMA(Al[0][1], Bh1, acc0);
            acc1 = MFMA(Ah[1][0], Bh0, acc1); acc1 = MFMA(Ah[1][1], Bh1, acc1);
            acc1 = MFMA(Ah[1][0], Bl0, acc1); acc1 = MFMA(Al[1][0], Bh0, acc1);
            acc1 = MFMA(Ah[1][1], Bl1, acc1); acc1 = MFMA(Al[1][1], Bh1, acc1);
#pragma unroll
            for (int reg = 0; reg < 4; ++reg) {
                UPD(reg,     __fmaf_rn(-2.0f, acc0[reg], c2v));
                UPD(4 + reg, __fmaf_rn(-2.0f, acc1[reg], c2v));
            }
            codef += 16.f;
        }
    }
#undef UPD

    // reduce (b1, bk, b2) across the 16 lanes holding one row's 16 col-classes
#pragma unroll
    for (int i = 0; i < 8; ++i) {
        float v1 = b1[i], v2 = b2[i], vk = bk[i];
#pragma unroll
        for (int m = 1; m < 16; m <<= 1) {
            const float o1 = __shfl_xor(v1, m);
            const float o2 = __shfl_xor(v2, m);
            const float ok = __shfl_xor(vk, m);
            v2 = fminf(fminf(v2, o2), fmaxf(v1, o1));
            if (o1 < v1) vk = ok;               // tie keeps own; tie => flagged anyway
            v1 = fminf(v1, o1);
        }
        if (col == 0) {
            const int rt = i >> 2, reg = i & 3;
            const int row = rowbase + rt * 16 + g * 4 + reg;
            out_idx[row] = vk;
            flags[row] = (v2 - v1 <= MARGIN) ? 1 : 0;
        }
    }
}

// ---- exact fix-up for flagged rows: one wave per row, verbatim reference math ----
__global__ __launch_bounds__(256) void fix_kernel(
        const float* __restrict__ z, const float* __restrict__ cb,
        const float* __restrict__ c2, const unsigned char* __restrict__ flags,
        float* __restrict__ out_idx)
{
    __shared__ int q[256];
    __shared__ int qn;
    if (threadIdx.x == 0) qn = 0;
    __syncthreads();
    const int r = blockIdx.x * 256 + threadIdx.x;
    if (flags[r]) { int p = atomicAdd(&qn, 1); q[p] = r; }
    __syncthreads();
    const int n = qn;
    const int wave = threadIdx.x >> 6, lane = threadIdx.x & 63;
    for (int i = wave; i < n; i += 4) {
        const int row = q[i];
        float zr[DIM];
        const float4* zv = (const float4*)(z + (size_t)row * DIM);
#pragma unroll
        for (int v = 0; v < 16; ++v) {
            float4 f = zv[v];
            zr[4 * v] = f.x; zr[4 * v + 1] = f.y; zr[4 * v + 2] = f.z; zr[4 * v + 3] = f.w;
        }
        // z2: numpy pairwise, 8 accumulators (identical to verified path)
        float ra[8];
#pragma unroll
        for (int j = 0; j < 8; ++j) ra[j] = __fmul_rn(zr[j], zr[j]);
#pragma unroll
        for (int d = 8; d < DIM; d += 8) {
#pragma unroll
            for (int j = 0; j < 8; ++j) ra[j] = __fadd_rn(ra[j], __fmul_rn(zr[d + j], zr[d + j]));
        }
        const float z2 = __fadd_rn(__fadd_rn(__fadd_rn(ra[0], ra[1]), __fadd_rn(ra[2], ra[3])),
                                   __fadd_rn(__fadd_rn(ra[4], ra[5]), __fadd_rn(ra[6], ra[7])));
        float best = __builtin_inff();
        int bestk = NCODE;
#pragma unroll 1
        for (int kk = 0; kk < 16; kk += 2) {        // lane owns codes [lane*16, lane*16+16)
            const int k0 = lane * 16 + kk;
            const float* c0 = cb + (size_t)k0 * DIM;
            const float* c1 = c0 + DIM;
            float a0 = 0.f, a1 = 0.f;
#pragma unroll
            for (int d = 0; d < DIM; ++d) {          // sequential FMA, sgemm order
                a0 = __fmaf_rn(zr[d], c0[d], a0);
                a1 = __fmaf_rn(zr[d], c1[d], a1);
            }
            const float d0 = __fadd_rn(__fmaf_rn(-2.0f, a0, z2), c2[k0]);
            const float d1 = __fadd_rn(__fmaf_rn(-2.0f, a1, z2), c2[k0 + 1]);
            if (d0 < best) { best = d0; bestk = k0; }
            if (d1 < best) { best = d1; bestk = k0 + 1; }
        }
#pragma unroll
        for (int m = 1; m < 64; m <<= 1) {           // exact cross-lane min, first-index ties
            const float ob = __shfl_xor(best, m);
            const int   ok = __shfl_xor(bestk, m);
            if (ob < best || (ob == best && ok < bestk)) { best = ob; bestk = ok; }
        }
        if (lane == 0) out_idx[row] = (float)bestk;
    }
}

// ---- epilogue: gather z_q, straight-through output, loss partial (verbatim math) ----
__global__ __launch_bounds__(BLOCK) void emit_kernel(
        const float* __restrict__ z, const float* __restrict__ cb,
        const float* __restrict__ out_idx, float* __restrict__ out_zq,
        double* __restrict__ partial)
{
    const int b = blockIdx.x * BLOCK + threadIdx.x;
    const int bestk = (int)out_idx[b];
    const float* cq = cb + (size_t)bestk * DIM;
    const float4* zv = (const float4*)(z + (size_t)b * DIM);
    const float4* qv = (const float4*)cq;
    float4* ov = (float4*)(out_zq + (size_t)b * DIM);
    double lsum = 0.0;
#pragma unroll
    for (int i = 0; i < DIM / 4; ++i) {
        float4 qq = qv[i], zl = zv[i];
        float qa[4] = {qq.x, qq.y, qq.z, qq.w};
        float za[4] = {zl.x, zl.y, zl.z, zl.w};
        float o[4];
#pragma unroll
        for (int j = 0; j < 4; ++j) {
            const float t = __fsub_rn(qa[j], za[j]);
            o[j] = __fadd_rn(za[j], t);
            lsum += (double)t * (double)t;
        }
        float4 vv; vv.x = o[0]; vv.y = o[1]; vv.z = o[2]; vv.w = o[3];
        ov[i] = vv;
    }

    __shared__ double sred[BLOCK];
    sred[threadIdx.x] = lsum;
    __syncthreads();
#pragma unroll
    for (int s = BLOCK / 2; s > 0; s >>= 1) {
        if (threadIdx.x < s) sred[threadIdx.x] += sred[threadIdx.x + s];
        __syncthreads();
    }
    if (threadIdx.x == 0) partial[blockIdx.x] = sred[0];
}

__global__ void loss_kernel(const double* __restrict__ partial, float* __restrict__ out_loss) {
    __shared__ double sred[256];
    double s = 0.0;
    for (int i = threadIdx.x; i < NBLK; i += 256) s += partial[i];
    sred[threadIdx.x] = s;
    __syncthreads();
#pragma unroll
    for (int st = 128; st > 0; st >>= 1) {
        if (threadIdx.x < st) sred[threadIdx.x] += sred[threadIdx.x + st];
        __syncthreads();
    }
    if (threadIdx.x == 0) {
        const double mean = sred[0] / (double)((size_t)BATCH * DIM);
        const float L = (float)mean;
        out_loss[0] = __fadd_rn(L, __fmul_rn(0.25f, L));
    }
}

extern "C" void kernel_launch(void* const* d_in, const int* in_sizes, int n_in,
                              void* d_out, int out_size, void* d_ws, size_t ws_size,
                              hipStream_t stream) {
    (void)in_sizes; (void)n_in; (void)out_size; (void)ws_size;
    const float* z  = (const float*)d_in[0];
    const float* cb = (const float*)d_in[1];
    float* out      = (float*)d_out;
    float* out_zq   = out;
    float* out_loss = out + (size_t)BATCH * DIM;
    float* out_idx  = out + (size_t)BATCH * DIM + 1;
    double* partial = (double*)d_ws;
    float* c2       = (float*)((char*)d_ws + 8192);
    unsigned char* flags = (unsigned char*)d_ws + 12288;
    unsigned short* pack = (unsigned short*)((char*)d_ws + 12288 + (size_t)BATCH);

    c2_kernel<<<NCODE / 256, 256, 0, stream>>>(cb, c2);
    pack_kernel<<<16, 256, 0, stream>>>(cb, pack);
    screen_kernel<<<BATCH / 128, 256, 0, stream>>>(z, pack, c2, out_idx, flags);
    fix_kernel<<<BATCH / 256, 256, 0, stream>>>(z, cb, c2, flags, out_idx);
    emit_kernel<<<NBLK, BLOCK, 0, stream>>>(z, cb, out_idx, out_zq, partial);
    loss_kernel<<<1, 256, 0, stream>>>(partial, out_loss);
}

// Round 2
// 484.793 us; speedup vs baseline: 2.5089x; 2.5089x over previous
//
#include <hip/hip_runtime.h>

#define BATCH   262144
#define NCODE   1024
#define DIM     64
#define BLOCK   256
#define NBLK    (BATCH / BLOCK)   // 1024 blocks for epilogue/loss
#define MARGIN  4e-5f
#define QCAP    65536

// ws layout (bytes):
// [0, 8192)            double partial[1024]
// [8192, 12288)        float  c2[1024]
// [12288, 12292)       uint   qcount          (pad to 12544)
// [12544, 274688)      uchar  flags[262144]
// [274688, 536832)     ushort pack[131072]    -- codebook bf16 hi/lo, fragment-major
// [536832, 798976)     int    queue[65536]

typedef __attribute__((ext_vector_type(8))) short bf16x8;
typedef __attribute__((ext_vector_type(4))) float f32x4;

#define MFMA(a, b, c) __builtin_amdgcn_mfma_f32_16x16x32_bf16(a, b, c, 0, 0, 0)

// ---- exact c2 (numpy pairwise order, 8 accumulators) — verified ----
__global__ void c2_kernel(const float* __restrict__ cb, float* __restrict__ c2,
                          unsigned int* __restrict__ qcount) {
    int k = blockIdx.x * blockDim.x + threadIdx.x;
    if (k == 0) *qcount = 0u;             // re-zero queue each replay
    if (k >= NCODE) return;
    const float* row = cb + (size_t)k * DIM;
    float r[8];
#pragma unroll
    for (int j = 0; j < 8; ++j) r[j] = __fmul_rn(row[j], row[j]);
#pragma unroll
    for (int i = 8; i < DIM; i += 8) {
#pragma unroll
        for (int j = 0; j < 8; ++j) r[j] = __fadd_rn(r[j], __fmul_rn(row[i + j], row[i + j]));
    }
    c2[k] = __fadd_rn(__fadd_rn(__fadd_rn(r[0], r[1]), __fadd_rn(r[2], r[3])),
                      __fadd_rn(__fadd_rn(r[4], r[5]), __fadd_rn(r[6], r[7])));
}

// fp32 -> bf16 hi (RNE) + bf16 lo (RNE of exact residual)
__device__ __forceinline__ void split1(float f, unsigned short& h, unsigned short& l) {
    unsigned u = __float_as_uint(f);
    unsigned r = (u + 0x7fffu + ((u >> 16) & 1u)) >> 16;
    h = (unsigned short)r;
    float hf = __uint_as_float(r << 16);
    float lo = f - hf;                      // exact (Sterbenz)
    unsigned u2 = __float_as_uint(lo);
    l = (unsigned short)((u2 + 0x7fffu + ((u2 >> 16) & 1u)) >> 16);
}

// ---- pack codebook into fragment-major bf16 hi/lo ----
__global__ void pack_kernel(const float* __restrict__ cb, unsigned short* __restrict__ pack) {
    const int tid  = blockIdx.x * blockDim.x + threadIdx.x;   // 0..4095
    const int t    = tid >> 6, lane = tid & 63;
    const int c    = t * 16 + (lane & 15);
    const int g    = lane >> 4;
#pragma unroll
    for (int s = 0; s < 2; ++s) {
        const float* src = cb + (size_t)c * DIM + s * 32 + g * 8;
        bf16x8 hv, lv;
#pragma unroll
        for (int j = 0; j < 8; ++j) {
            unsigned short hh, ll; split1(src[j], hh, ll);
            hv[j] = (short)hh; lv[j] = (short)ll;
        }
        *(bf16x8*)(pack + ((size_t)(t * 4 + 2 * s + 0) * 64 + lane) * 8) = hv;
        *(bf16x8*)(pack + ((size_t)(t * 4 + 2 * s + 1) * 64 + lane) * 8) = lv;
    }
}

// ---- MFMA screening: per-row best/second-best of s(k) = c2[k] - 2*cross(k) ----
__global__ __launch_bounds__(256) void screen_kernel(
        const float* __restrict__ z, const unsigned short* __restrict__ pack,
        const float* __restrict__ c2, float* __restrict__ out_idx,
        unsigned char* __restrict__ flags, int* __restrict__ queue,
        unsigned int* __restrict__ qcount)
{
    __shared__ unsigned short lds[16384];       // 32 KB = 8 tiles * 4 KB
    const int tid  = threadIdx.x;
    const int lane = tid & 63, wid = tid >> 6;
    const int col  = lane & 15, g = lane >> 4;
    const int rowbase = blockIdx.x * 128 + wid * 32;

    // A-frags: A[row = lane&15][k = 32*s + 8*g + j], in VGPRs for whole kernel
    bf16x8 Ah[2][2], Al[2][2];
#pragma unroll
    for (int rt = 0; rt < 2; ++rt)
#pragma unroll
        for (int s = 0; s < 2; ++s) {
            const float* zp = z + (size_t)(rowbase + rt * 16 + col) * DIM + s * 32 + g * 8;
            float tmp[8];
            *(float4*)(tmp)     = ((const float4*)zp)[0];
            *(float4*)(tmp + 4) = ((const float4*)zp)[1];
            bf16x8 hv, lv;
#pragma unroll
            for (int j = 0; j < 8; ++j) {
                unsigned short hh, ll; split1(tmp[j], hh, ll);
                hv[j] = (short)hh; lv[j] = (short)ll;
            }
            Ah[rt][s] = hv; Al[rt][s] = lv;
        }

    float b1[8], b2[8], bk[8];
#pragma unroll
    for (int i = 0; i < 8; ++i) { b1[i] = __builtin_inff(); b2[i] = __builtin_inff(); bk[i] = 0.f; }
    float codef = (float)col;

#define UPD(i, sv) { const float s_ = (sv); const bool lt = s_ < b1[i]; \
                     b2[i] = fminf(b2[i], fmaxf(s_, b1[i])); \
                     bk[i] = lt ? codef : bk[i]; \
                     b1[i] = fminf(b1[i], s_); }

#pragma unroll 1
    for (int chunk = 0; chunk < 8; ++chunk) {
        if (chunk) __syncthreads();
        {   // stage 8 tiles (32 KB), fully coalesced
            const unsigned short* gs = pack + (size_t)chunk * 16384;
#pragma unroll
            for (int i = 0; i < 8; ++i) {
                const int seg = wid * 8 + i;
                bf16x8 v = *(const bf16x8*)(gs + seg * 512 + lane * 8);
                *(bf16x8*)(lds + seg * 512 + lane * 8) = v;
            }
        }
        // hoist this chunk's c2 values (one 64B line per tt, batched loads)
        float c2r[8];
#pragma unroll
        for (int tt = 0; tt < 8; ++tt) c2r[tt] = c2[(chunk * 8 + tt) * 16 + col];
        __syncthreads();
#pragma unroll
        for (int tt = 0; tt < 8; ++tt) {
            const unsigned short* lb = lds + tt * 2048;
            bf16x8 Bh0 = *(const bf16x8*)(lb +    0 + lane * 8);
            bf16x8 Bl0 = *(const bf16x8*)(lb +  512 + lane * 8);
            bf16x8 Bh1 = *(const bf16x8*)(lb + 1024 + lane * 8);
            bf16x8 Bl1 = *(const bf16x8*)(lb + 1536 + lane * 8);
            const float c2v = c2r[tt];
            f32x4 acc0 = {0.f, 0.f, 0.f, 0.f}, acc1 = {0.f, 0.f, 0.f, 0.f};
            acc0 = MFMA(Ah[0][0], Bh0, acc0); acc0 = MFMA(Ah[0][1], Bh1, acc0);
            acc0 = MFMA(Ah[0][0], Bl0, acc0); acc0 = MFMA(Al[0][0], Bh0, acc0);
            acc0 = MFMA(Ah[0][1], Bl1, acc0); acc0 = MFMA(Al[0][1], Bh1, acc0);
            acc1 = MFMA(Ah[1][0], Bh0, acc1); acc1 = MFMA(Ah[1][1], Bh1, acc1);
            acc1 = MFMA(Ah[1][0], Bl0, acc1); acc1 = MFMA(Al[1][0], Bh0, acc1);
            acc1 = MFMA(Ah[1][1], Bl1, acc1); acc1 = MFMA(Al[1][1], Bh1, acc1);
#pragma unroll
            for (int reg = 0; reg < 4; ++reg) {
                UPD(reg,     __fmaf_rn(-2.0f, acc0[reg], c2v));
                UPD(4 + reg, __fmaf_rn(-2.0f, acc1[reg], c2v));
            }
            codef += 16.f;
        }
    }
#undef UPD

    // reduce (b1, bk, b2) across the 16 lanes holding one row's 16 col-classes
#pragma unroll
    for (int i = 0; i < 8; ++i) {
        float v1 = b1[i], v2 = b2[i], vk = bk[i];
#pragma unroll
        for (int m = 1; m < 16; m <<= 1) {
            const float o1 = __shfl_xor(v1, m);
            const float o2 = __shfl_xor(v2, m);
            const float ok = __shfl_xor(vk, m);
            v2 = fminf(fminf(v2, o2), fmaxf(v1, o1));
            if (o1 < v1) vk = ok;
            v1 = fminf(v1, o1);
        }
        if (col == 0) {
            const int rt = i >> 2, reg = i & 3;
            const int row = rowbase + rt * 16 + g * 4 + reg;
            out_idx[row] = vk;
            const bool f = (v2 - v1 <= MARGIN);
            flags[row] = f ? 1 : 0;
            if (f) {
                unsigned int p = atomicAdd(qcount, 1u);
                if (p < QCAP) queue[p] = row;
            }
        }
    }
}

// ---- exact fix-up: one block per flagged row, verbatim reference math ----
__device__ void fix_row(int row, const float* __restrict__ z, const float* __restrict__ cb,
                        const float* __restrict__ c2, float* __restrict__ out_idx,
                        float* zs, float* rv, int* ri)
{
    const int tid = threadIdx.x;
    __syncthreads();                        // zs safe to overwrite
    if (tid < 16) ((float4*)zs)[tid] = ((const float4*)(z + (size_t)row * DIM))[tid];
    __syncthreads();
    float zr[DIM];
#pragma unroll
    for (int i = 0; i < 16; ++i) {
        float4 v = ((const float4*)zs)[i];
        zr[4 * i] = v.x; zr[4 * i + 1] = v.y; zr[4 * i + 2] = v.z; zr[4 * i + 3] = v.w;
    }
    // z2: numpy pairwise, 8 accumulators (verified path)
    float ra[8];
#pragma unroll
    for (int j = 0; j < 8; ++j) ra[j] = __fmul_rn(zr[j], zr[j]);
#pragma unroll
    for (int d = 8; d < DIM; d += 8) {
#pragma unroll
        for (int j = 0; j < 8; ++j) ra[j] = __fadd_rn(ra[j], __fmul_rn(zr[d + j], zr[d + j]));
    }
    const float z2 = __fadd_rn(__fadd_rn(__fadd_rn(ra[0], ra[1]), __fadd_rn(ra[2], ra[3])),
                               __fadd_rn(__fadd_rn(ra[4], ra[5]), __fadd_rn(ra[6], ra[7])));
    // 4 contiguous codes per thread: k = 4*tid + j; sequential-FMA chain per code
    const int k0 = tid * 4;
    const float* cp = cb + (size_t)k0 * DIM;
    float a[4] = {0.f, 0.f, 0.f, 0.f};
#pragma unroll
    for (int d = 0; d < DIM; ++d) {
#pragma unroll
        for (int j = 0; j < 4; ++j) a[j] = __fmaf_rn(zr[d], cp[(size_t)j * DIM + d], a[j]);
    }
    float best = __builtin_inff();
    int bestk = NCODE;
#pragma unroll
    for (int j = 0; j < 4; ++j) {
        const float dist = __fadd_rn(__fmaf_rn(-2.0f, a[j], z2), c2[k0 + j]);
        if (dist < best) { best = dist; bestk = k0 + j; }   // strict <, ascending k
    }
    rv[tid] = best; ri[tid] = bestk;
    __syncthreads();
#pragma unroll
    for (int s = 128; s > 0; s >>= 1) {
        if (tid < s) {
            const float ov = rv[tid + s]; const int oi = ri[tid + s];
            if (ov < rv[tid] || (ov == rv[tid] && oi < ri[tid])) { rv[tid] = ov; ri[tid] = oi; }
        }
        __syncthreads();
    }
    if (tid == 0) out_idx[row] = (float)ri[0];
}

__global__ __launch_bounds__(256) void fix_kernel(
        const float* __restrict__ z, const float* __restrict__ cb,
        const float* __restrict__ c2, const int* __restrict__ queue,
        const unsigned int* __restrict__ qcount, const unsigned char* __restrict__ flags,
        float* __restrict__ out_idx)
{
    __shared__ float zs[DIM];
    __shared__ float rv[256];
    __shared__ int   ri[256];
    const unsigned int nq = *qcount;
    if (nq <= QCAP) {
        for (unsigned int qi = blockIdx.x; qi < nq; qi += gridDim.x)
            fix_row(queue[qi], z, cb, c2, out_idx, zs, rv, ri);
    } else {
        // overflow fallback (never expected): scan flags
        for (int row = blockIdx.x; row < BATCH; row += (int)gridDim.x)
            if (flags[row]) fix_row(row, z, cb, c2, out_idx, zs, rv, ri);
    }
}

// ---- epilogue: gather z_q, straight-through output, loss partial (verbatim) ----
__global__ __launch_bounds__(BLOCK) void emit_kernel(
        const float* __restrict__ z, const float* __restrict__ cb,
        const float* __restrict__ out_idx, float* __restrict__ out_zq,
        double* __restrict__ partial)
{
    const int b = blockIdx.x * BLOCK + threadIdx.x;
    const int bestk = (int)out_idx[b];
    const float* cq = cb + (size_t)bestk * DIM;
    const float4* zv = (const float4*)(z + (size_t)b * DIM);
    const float4* qv = (const float4*)cq;
    float4* ov = (float4*)(out_zq + (size_t)b * DIM);
    double lsum = 0.0;
#pragma unroll
    for (int i = 0; i < DIM / 4; ++i) {
        float4 qq = qv[i], zl = zv[i];
        float qa[4] = {qq.x, qq.y, qq.z, qq.w};
        float za[4] = {zl.x, zl.y, zl.z, zl.w};
        float o[4];
#pragma unroll
        for (int j = 0; j < 4; ++j) {
            const float t = __fsub_rn(qa[j], za[j]);
            o[j] = __fadd_rn(za[j], t);
            lsum += (double)t * (double)t;
        }
        float4 vv; vv.x = o[0]; vv.y = o[1]; vv.z = o[2]; vv.w = o[3];
        ov[i] = vv;
    }

    __shared__ double sred[BLOCK];
    sred[threadIdx.x] = lsum;
    __syncthreads();
#pragma unroll
    for (int s = BLOCK / 2; s > 0; s >>= 1) {
        if (threadIdx.x < s) sred[threadIdx.x] += sred[threadIdx.x + s];
        __syncthreads();
    }
    if (threadIdx.x == 0) partial[blockIdx.x] = sred[0];
}

__global__ void loss_kernel(const double* __restrict__ partial, float* __restrict__ out_loss) {
    __shared__ double sred[256];
    double s = 0.0;
    for (int i = threadIdx.x; i < NBLK; i += 256) s += partial[i];
    sred[threadIdx.x] = s;
    __syncthreads();
#pragma unroll
    for (int st = 128; st > 0; st >>= 1) {
        if (threadIdx.x < st) sred[threadIdx.x] += sred[threadIdx.x + st];
        __syncthreads();
    }
    if (threadIdx.x == 0) {
        const double mean = sred[0] / (double)((size_t)BATCH * DIM);
        const float L = (float)mean;
        out_loss[0] = __fadd_rn(L, __fmul_rn(0.25f, L));
    }
}

extern "C" void kernel_launch(void* const* d_in, const int* in_sizes, int n_in,
                              void* d_out, int out_size, void* d_ws, size_t ws_size,
                              hipStream_t stream) {
    (void)in_sizes; (void)n_in; (void)out_size; (void)ws_size;
    const float* z  = (const float*)d_in[0];
    const float* cb = (const float*)d_in[1];
    float* out      = (float*)d_out;
    float* out_zq   = out;
    float* out_loss = out + (size_t)BATCH * DIM;
    float* out_idx  = out + (size_t)BATCH * DIM + 1;
    double* partial = (double*)d_ws;
    float* c2       = (float*)((char*)d_ws + 8192);
    unsigned int* qcount = (unsigned int*)((char*)d_ws + 12288);
    unsigned char* flags = (unsigned char*)d_ws + 12544;
    unsigned short* pack = (unsigned short*)((char*)d_ws + 274688);
    int* queue      = (int*)((char*)d_ws + 536832);

    c2_kernel<<<NCODE / 256, 256, 0, stream>>>(cb, c2, qcount);
    pack_kernel<<<16, 256, 0, stream>>>(cb, pack);
    screen_kernel<<<BATCH / 128, 256, 0, stream>>>(z, pack, c2, out_idx, flags, queue, qcount);
    fix_kernel<<<2048, 256, 0, stream>>>(z, cb, c2, queue, qcount, flags, out_idx);
    emit_kernel<<<NBLK, BLOCK, 0, stream>>>(z, cb, out_idx, out_zq, partial);
    loss_kernel<<<1, 256, 0, stream>>>(partial, out_loss);
}

// Round 3
// 314.805 us; speedup vs baseline: 3.8637x; 1.5400x over previous
//
#include <hip/hip_runtime.h>

#define BATCH   262144
#define NCODE   1024
#define DIM     64
#define BLOCK   256
#define NBLK    (BATCH / BLOCK)   // 1024 blocks for epilogue/loss
#define MARGIN  4e-5f
#define QCAP    65536

// ws layout (bytes):
// [0, 8192)            double partial[1024]
// [8192, 12288)        float  c2[1024]
// [12288, 12292)       uint   qcount          (pad to 12544)
// [12544, 274688)      uchar  flags[262144]
// [274688, 536832)     ushort pack[131072]    -- codebook bf16 hi/lo, fragment-major
// [536832, 798976)     int    queue[65536]
// [798976, 1061120)    float  cbT[65536]      -- codebook transposed [d][k]

typedef __attribute__((ext_vector_type(8))) short bf16x8;
typedef __attribute__((ext_vector_type(4))) float f32x4;

#define MFMA(a, b, c) __builtin_amdgcn_mfma_f32_16x16x32_bf16(a, b, c, 0, 0, 0)

// ---- exact c2 (numpy pairwise order, 8 accumulators) — verified ----
__global__ void c2_kernel(const float* __restrict__ cb, float* __restrict__ c2,
                          unsigned int* __restrict__ qcount) {
    int k = blockIdx.x * blockDim.x + threadIdx.x;
    if (k == 0) *qcount = 0u;             // re-zero queue each replay
    if (k >= NCODE) return;
    const float* row = cb + (size_t)k * DIM;
    float r[8];
#pragma unroll
    for (int j = 0; j < 8; ++j) r[j] = __fmul_rn(row[j], row[j]);
#pragma unroll
    for (int i = 8; i < DIM; i += 8) {
#pragma unroll
        for (int j = 0; j < 8; ++j) r[j] = __fadd_rn(r[j], __fmul_rn(row[i + j], row[i + j]));
    }
    c2[k] = __fadd_rn(__fadd_rn(__fadd_rn(r[0], r[1]), __fadd_rn(r[2], r[3])),
                      __fadd_rn(__fadd_rn(r[4], r[5]), __fadd_rn(r[6], r[7])));
}

// ---- transpose codebook: cbT[d*1024 + k] = cb[k*64 + d] ----
__global__ void cbt_kernel(const float* __restrict__ cb, float* __restrict__ cbT) {
    const int gid = blockIdx.x * blockDim.x + threadIdx.x;   // 0..65535
    const int k = gid >> 6, d = gid & 63;
    cbT[(size_t)d * NCODE + k] = cb[gid];
}

// fp32 -> bf16 hi (RNE) + bf16 lo (RNE of exact residual)
__device__ __forceinline__ void split1(float f, unsigned short& h, unsigned short& l) {
    unsigned u = __float_as_uint(f);
    unsigned r = (u + 0x7fffu + ((u >> 16) & 1u)) >> 16;
    h = (unsigned short)r;
    float hf = __uint_as_float(r << 16);
    float lo = f - hf;                      // exact (Sterbenz)
    unsigned u2 = __float_as_uint(lo);
    l = (unsigned short)((u2 + 0x7fffu + ((u2 >> 16) & 1u)) >> 16);
}

// ---- pack codebook into fragment-major bf16 hi/lo ----
__global__ void pack_kernel(const float* __restrict__ cb, unsigned short* __restrict__ pack) {
    const int tid  = blockIdx.x * blockDim.x + threadIdx.x;   // 0..4095
    const int t    = tid >> 6, lane = tid & 63;
    const int c    = t * 16 + (lane & 15);
    const int g    = lane >> 4;
#pragma unroll
    for (int s = 0; s < 2; ++s) {
        const float* src = cb + (size_t)c * DIM + s * 32 + g * 8;
        bf16x8 hv, lv;
#pragma unroll
        for (int j = 0; j < 8; ++j) {
            unsigned short hh, ll; split1(src[j], hh, ll);
            hv[j] = (short)hh; lv[j] = (short)ll;
        }
        *(bf16x8*)(pack + ((size_t)(t * 4 + 2 * s + 0) * 64 + lane) * 8) = hv;
        *(bf16x8*)(pack + ((size_t)(t * 4 + 2 * s + 1) * 64 + lane) * 8) = lv;
    }
}

// ---- MFMA screening: per-row best/second-best of s(k) = c2[k] - 2*cross(k) ----
__global__ __launch_bounds__(256) void screen_kernel(
        const float* __restrict__ z, const unsigned short* __restrict__ pack,
        const float* __restrict__ c2, float* __restrict__ out_idx,
        unsigned char* __restrict__ flags, int* __restrict__ queue,
        unsigned int* __restrict__ qcount)
{
    __shared__ unsigned short lds[16384];       // 32 KB = 8 tiles * 4 KB
    const int tid  = threadIdx.x;
    const int lane = tid & 63, wid = tid >> 6;
    const int col  = lane & 15, g = lane >> 4;
    const int rowbase = blockIdx.x * 128 + wid * 32;

    // A-frags: A[row = lane&15][k = 32*s + 8*g + j], in VGPRs for whole kernel
    bf16x8 Ah[2][2], Al[2][2];
#pragma unroll
    for (int rt = 0; rt < 2; ++rt)
#pragma unroll
        for (int s = 0; s < 2; ++s) {
            const float* zp = z + (size_t)(rowbase + rt * 16 + col) * DIM + s * 32 + g * 8;
            float tmp[8];
            *(float4*)(tmp)     = ((const float4*)zp)[0];
            *(float4*)(tmp + 4) = ((const float4*)zp)[1];
            bf16x8 hv, lv;
#pragma unroll
            for (int j = 0; j < 8; ++j) {
                unsigned short hh, ll; split1(tmp[j], hh, ll);
                hv[j] = (short)hh; lv[j] = (short)ll;
            }
            Ah[rt][s] = hv; Al[rt][s] = lv;
        }

    float b1[8], b2[8], bk[8];
#pragma unroll
    for (int i = 0; i < 8; ++i) { b1[i] = __builtin_inff(); b2[i] = __builtin_inff(); bk[i] = 0.f; }
    float codef = (float)col;

#define UPD(i, sv) { const float s_ = (sv); const bool lt = s_ < b1[i]; \
                     b2[i] = fminf(b2[i], fmaxf(s_, b1[i])); \
                     bk[i] = lt ? codef : bk[i]; \
                     b1[i] = fminf(b1[i], s_); }

#pragma unroll 1
    for (int chunk = 0; chunk < 8; ++chunk) {
        if (chunk) __syncthreads();
        {   // stage 8 tiles (32 KB), fully coalesced
            const unsigned short* gs = pack + (size_t)chunk * 16384;
#pragma unroll
            for (int i = 0; i < 8; ++i) {
                const int seg = wid * 8 + i;
                bf16x8 v = *(const bf16x8*)(gs + seg * 512 + lane * 8);
                *(bf16x8*)(lds + seg * 512 + lane * 8) = v;
            }
        }
        // hoist this chunk's c2 values
        float c2r[8];
#pragma unroll
        for (int tt = 0; tt < 8; ++tt) c2r[tt] = c2[(chunk * 8 + tt) * 16 + col];
        __syncthreads();
#pragma unroll
        for (int tt = 0; tt < 8; ++tt) {
            const unsigned short* lb = lds + tt * 2048;
            bf16x8 Bh0 = *(const bf16x8*)(lb +    0 + lane * 8);
            bf16x8 Bl0 = *(const bf16x8*)(lb +  512 + lane * 8);
            bf16x8 Bh1 = *(const bf16x8*)(lb + 1024 + lane * 8);
            bf16x8 Bl1 = *(const bf16x8*)(lb + 1536 + lane * 8);
            const float c2v = c2r[tt];
            f32x4 acc0 = {0.f, 0.f, 0.f, 0.f}, acc1 = {0.f, 0.f, 0.f, 0.f};
            acc0 = MFMA(Ah[0][0], Bh0, acc0); acc0 = MFMA(Ah[0][1], Bh1, acc0);
            acc0 = MFMA(Ah[0][0], Bl0, acc0); acc0 = MFMA(Al[0][0], Bh0, acc0);
            acc0 = MFMA(Ah[0][1], Bl1, acc0); acc0 = MFMA(Al[0][1], Bh1, acc0);
            acc1 = MFMA(Ah[1][0], Bh0, acc1); acc1 = MFMA(Ah[1][1], Bh1, acc1);
            acc1 = MFMA(Ah[1][0], Bl0, acc1); acc1 = MFMA(Al[1][0], Bh0, acc1);
            acc1 = MFMA(Ah[1][1], Bl1, acc1); acc1 = MFMA(Al[1][1], Bh1, acc1);
#pragma unroll
            for (int reg = 0; reg < 4; ++reg) {
                UPD(reg,     __fmaf_rn(-2.0f, acc0[reg], c2v));
                UPD(4 + reg, __fmaf_rn(-2.0f, acc1[reg], c2v));
            }
            codef += 16.f;
        }
    }
#undef UPD

    // reduce (b1, bk, b2) across the 16 lanes holding one row's 16 col-classes
#pragma unroll
    for (int i = 0; i < 8; ++i) {
        float v1 = b1[i], v2 = b2[i], vk = bk[i];
#pragma unroll
        for (int m = 1; m < 16; m <<= 1) {
            const float o1 = __shfl_xor(v1, m);
            const float o2 = __shfl_xor(v2, m);
            const float ok = __shfl_xor(vk, m);
            v2 = fminf(fminf(v2, o2), fmaxf(v1, o1));
            if (o1 < v1) vk = ok;
            v1 = fminf(v1, o1);
        }
        if (col == 0) {
            const int rt = i >> 2, reg = i & 3;
            const int row = rowbase + rt * 16 + g * 4 + reg;
            out_idx[row] = vk;
            const bool f = (v2 - v1 <= MARGIN);
            flags[row] = f ? 1 : 0;
            if (f) {
                unsigned int p = atomicAdd(qcount, 1u);
                if (p < QCAP) queue[p] = row;
            }
        }
    }
}

// ---- exact fix-up: one block per flagged row, coalesced via transposed codebook ----
__device__ void fix_row(int row, const float* __restrict__ z, const float* __restrict__ cbT,
                        const float* __restrict__ c2, float* __restrict__ out_idx,
                        float* zs, float* rv, int* ri)
{
    const int tid = threadIdx.x;
    __syncthreads();                        // zs safe to overwrite
    if (tid < 16) ((float4*)zs)[tid] = ((const float4*)(z + (size_t)row * DIM))[tid];
    __syncthreads();
    // z2: numpy pairwise, 8 accumulators (verified path), from LDS broadcast
    float ra[8];
#pragma unroll
    for (int j = 0; j < 8; ++j) ra[j] = __fmul_rn(zs[j], zs[j]);
#pragma unroll
    for (int d = 8; d < DIM; d += 8) {
#pragma unroll
        for (int j = 0; j < 8; ++j) ra[j] = __fadd_rn(ra[j], __fmul_rn(zs[d + j], zs[d + j]));
    }
    const float z2 = __fadd_rn(__fadd_rn(__fadd_rn(ra[0], ra[1]), __fadd_rn(ra[2], ra[3])),
                               __fadd_rn(__fadd_rn(ra[4], ra[5]), __fadd_rn(ra[6], ra[7])));
    // 4 contiguous codes per thread: k = 4*tid + j, via cbT (coalesced float4 per d)
    float a[4] = {0.f, 0.f, 0.f, 0.f};
#pragma unroll 8
    for (int d = 0; d < DIM; ++d) {
        const float zd = zs[d];
        const float4 cv = ((const float4*)(cbT + (size_t)d * NCODE))[tid];
        a[0] = __fmaf_rn(zd, cv.x, a[0]);
        a[1] = __fmaf_rn(zd, cv.y, a[1]);
        a[2] = __fmaf_rn(zd, cv.z, a[2]);
        a[3] = __fmaf_rn(zd, cv.w, a[3]);
    }
    const int k0 = tid * 4;
    float best = __builtin_inff();
    int bestk = NCODE;
#pragma unroll
    for (int j = 0; j < 4; ++j) {
        const float dist = __fadd_rn(__fmaf_rn(-2.0f, a[j], z2), c2[k0 + j]);
        if (dist < best) { best = dist; bestk = k0 + j; }   // strict <, ascending k
    }
    rv[tid] = best; ri[tid] = bestk;
    __syncthreads();
#pragma unroll
    for (int s = 128; s > 0; s >>= 1) {
        if (tid < s) {
            const float ov = rv[tid + s]; const int oi = ri[tid + s];
            if (ov < rv[tid] || (ov == rv[tid] && oi < ri[tid])) { rv[tid] = ov; ri[tid] = oi; }
        }
        __syncthreads();
    }
    if (tid == 0) out_idx[row] = (float)ri[0];
}

__global__ __launch_bounds__(256) void fix_kernel(
        const float* __restrict__ z, const float* __restrict__ cbT,
        const float* __restrict__ c2, const int* __restrict__ queue,
        const unsigned int* __restrict__ qcount, const unsigned char* __restrict__ flags,
        float* __restrict__ out_idx)
{
    __shared__ float zs[DIM];
    __shared__ float rv[256];
    __shared__ int   ri[256];
    const unsigned int nq = *qcount;
    if (nq <= QCAP) {
        for (unsigned int qi = blockIdx.x; qi < nq; qi += gridDim.x)
            fix_row(queue[qi], z, cbT, c2, out_idx, zs, rv, ri);
    } else {
        // overflow fallback (never expected): scan flags
        for (int row = blockIdx.x; row < BATCH; row += (int)gridDim.x)
            if (flags[row]) fix_row(row, z, cbT, c2, out_idx, zs, rv, ri);
    }
}

// ---- epilogue: gather z_q, straight-through output, loss partial (verbatim) ----
__global__ __launch_bounds__(BLOCK) void emit_kernel(
        const float* __restrict__ z, const float* __restrict__ cb,
        const float* __restrict__ out_idx, float* __restrict__ out_zq,
        double* __restrict__ partial)
{
    const int b = blockIdx.x * BLOCK + threadIdx.x;
    const int bestk = (int)out_idx[b];
    const float* cq = cb + (size_t)bestk * DIM;
    const float4* zv = (const float4*)(z + (size_t)b * DIM);
    const float4* qv = (const float4*)cq;
    float4* ov = (float4*)(out_zq + (size_t)b * DIM);
    double lsum = 0.0;
#pragma unroll
    for (int i = 0; i < DIM / 4; ++i) {
        float4 qq = qv[i], zl = zv[i];
        float qa[4] = {qq.x, qq.y, qq.z, qq.w};
        float za[4] = {zl.x, zl.y, zl.z, zl.w};
        float o[4];
#pragma unroll
        for (int j = 0; j < 4; ++j) {
            const float t = __fsub_rn(qa[j], za[j]);
            o[j] = __fadd_rn(za[j], t);
            lsum += (double)t * (double)t;
        }
        float4 vv; vv.x = o[0]; vv.y = o[1]; vv.z = o[2]; vv.w = o[3];
        ov[i] = vv;
    }

    __shared__ double sred[BLOCK];
    sred[threadIdx.x] = lsum;
    __syncthreads();
#pragma unroll
    for (int s = BLOCK / 2; s > 0; s >>= 1) {
        if (threadIdx.x < s) sred[threadIdx.x] += sred[threadIdx.x + s];
        __syncthreads();
    }
    if (threadIdx.x == 0) partial[blockIdx.x] = sred[0];
}

__global__ void loss_kernel(const double* __restrict__ partial, float* __restrict__ out_loss) {
    __shared__ double sred[256];
    double s = 0.0;
    for (int i = threadIdx.x; i < NBLK; i += 256) s += partial[i];
    sred[threadIdx.x] = s;
    __syncthreads();
#pragma unroll
    for (int st = 128; st > 0; st >>= 1) {
        if (threadIdx.x < st) sred[threadIdx.x] += sred[threadIdx.x + st];
        __syncthreads();
    }
    if (threadIdx.x == 0) {
        const double mean = sred[0] / (double)((size_t)BATCH * DIM);
        const float L = (float)mean;
        out_loss[0] = __fadd_rn(L, __fmul_rn(0.25f, L));
    }
}

extern "C" void kernel_launch(void* const* d_in, const int* in_sizes, int n_in,
                              void* d_out, int out_size, void* d_ws, size_t ws_size,
                              hipStream_t stream) {
    (void)in_sizes; (void)n_in; (void)out_size; (void)ws_size;
    const float* z  = (const float*)d_in[0];
    const float* cb = (const float*)d_in[1];
    float* out      = (float*)d_out;
    float* out_zq   = out;
    float* out_loss = out + (size_t)BATCH * DIM;
    float* out_idx  = out + (size_t)BATCH * DIM + 1;
    double* partial = (double*)d_ws;
    float* c2       = (float*)((char*)d_ws + 8192);
    unsigned int* qcount = (unsigned int*)((char*)d_ws + 12288);
    unsigned char* flags = (unsigned char*)d_ws + 12544;
    unsigned short* pack = (unsigned short*)((char*)d_ws + 274688);
    int* queue      = (int*)((char*)d_ws + 536832);
    float* cbT      = (float*)((char*)d_ws + 798976);

    c2_kernel<<<NCODE / 256, 256, 0, stream>>>(cb, c2, qcount);
    cbt_kernel<<<256, 256, 0, stream>>>(cb, cbT);
    pack_kernel<<<16, 256, 0, stream>>>(cb, pack);
    screen_kernel<<<BATCH / 128, 256, 0, stream>>>(z, pack, c2, out_idx, flags, queue, qcount);
    fix_kernel<<<2048, 256, 0, stream>>>(z, cbT, c2, queue, qcount, flags, out_idx);
    emit_kernel<<<NBLK, BLOCK, 0, stream>>>(z, cb, out_idx, out_zq, partial);
    loss_kernel<<<1, 256, 0, stream>>>(partial, out_loss);
}